// Round 8
// baseline (528.812 us; speedup 1.0000x reference)
//
#include <hip/hip_runtime.h>

#define EMBED 1024
#define BATCH 4
#define SEQ   4096
#define ROWS  (BATCH*SEQ)   // 16384
#define CAP   128           // candidate slots per row (r3-r12 proven)
#define TSCAN_SC 140.0f     // scan margin, SCALED units: 50 (proven) + 5*sqrt(2)*sigma_q (~11)
#define TRES  160.0f        // rescore margin, scaled: 75 (proven) + i8 score-noise allowance

typedef __attribute__((ext_vector_type(8))) short bf16x8;
typedef __attribute__((ext_vector_type(4))) float f32x4;
typedef __attribute__((ext_vector_type(4))) int   i32x4;

static __device__ __forceinline__ unsigned short f2bf(float x) {
    unsigned u = __float_as_uint(x);
    u = (u + 0x7fffu + ((u >> 16) & 1u)) >> 16;
    return (unsigned short)u;
}
static __device__ __forceinline__ float bf2f(unsigned short h) {
    return __uint_as_float(((unsigned)h) << 16);
}
static __device__ __forceinline__ void split2(float x, unsigned short& hi, unsigned short& lo) {
    hi = f2bf(x);
    lo = f2bf(x - bf2f(hi));
}

// ---- async global->LDS, one 16B segment ----
static __device__ __forceinline__ void gll(const unsigned short* g, unsigned short* l) {
    __builtin_amdgcn_global_load_lds(
        (const __attribute__((address_space(1))) unsigned int*)g,
        (__attribute__((address_space(3))) unsigned int*)l, 16, 0, 0);
}
static __device__ __forceinline__ void gllb(const unsigned char* g, unsigned char* l) {
    __builtin_amdgcn_global_load_lds(
        (const __attribute__((address_space(1))) unsigned int*)g,
        (__attribute__((address_space(3))) unsigned int*)l, 16, 0, 0);
}
// ---- 128x32-short tile stager, 4-segment swizzle (r3-proven, 0 conflicts) ----
static __device__ __forceinline__ void stage_tile(unsigned short (*lds)[32],
                                                  const unsigned short* gbase,
                                                  int wave, int lane) {
#pragma unroll
    for (int c = 0; c < 2; c++) {
        int L = wave * 128 + c * 64 + lane;
        int r = L >> 2, s = L & 3;
        int g = (s - (r >> 1)) & 3;
        gll(gbase + (size_t)r * EMBED + g * 8, &lds[r][s * 8]);
    }
}
static __device__ __forceinline__ bf16x8 read_frag(const unsigned short (*lds)[32], int r, int kq) {
    int s = ((kq >> 3) + (r >> 1)) & 3;
    return *(const bf16x8*)&lds[r][s * 8];
}
// ---- byte-identical i8 variants: 128 rows x 64 i8 = 4 x 16B segs/row, same swizzle ----
static __device__ __forceinline__ void stage_tile8(unsigned char (*lds)[64],
                                                   const unsigned char* gbase,
                                                   int wave, int lane) {
#pragma unroll
    for (int c = 0; c < 2; c++) {
        int L = wave * 128 + c * 64 + lane;
        int r = L >> 2, s = L & 3;
        int g = (s - (r >> 1)) & 3;
        gllb(gbase + (size_t)r * EMBED + g * 16, &lds[r][s * 16]);
    }
}
static __device__ __forceinline__ i32x4 read_frag8(const unsigned char (*lds)[64], int r, int kseg) {
    int s = (kseg + (r >> 1)) & 3;
    return *(const i32x4*)&lds[r][s * 16];
}

// ---------------- prep: wv_bar[i] = mean_d Wv[i][d] ----------------
__global__ void k_wvbar(const float* __restrict__ Wv, float* __restrict__ wvbar) {
    int r = blockIdx.x, t = threadIdx.x;
    float s = 0.f;
    for (int c = t; c < EMBED; c += 256) s += Wv[(size_t)r * EMBED + c];
    for (int d = 1; d < 64; d <<= 1) s += __shfl_xor(s, d);
    __shared__ float ws_[4];
    if ((t & 63) == 0) ws_[t >> 6] = s;
    __syncthreads();
    if (t == 0) wvbar[r] = (ws_[0] + ws_[1] + ws_[2] + ws_[3]) * (1.0f / EMBED);
}

// ---------------- prep: row split + vmean + cnt zero + (optional) i8 row-quant of X ----------------
__global__ __launch_bounds__(256) void k_xsplit_vmean(
    const float* __restrict__ X, const float* __restrict__ wvbar,
    unsigned short* __restrict__ Xhi, unsigned short* __restrict__ Xlo,
    float* __restrict__ vmean, int* __restrict__ cnt,
    signed char* __restrict__ X8, float* __restrict__ scaleX) {
    int row = blockIdx.x, t = threadIdx.x;
    float4 x4 = *(const float4*)(X + (size_t)row * EMBED + t * 4);
    float4 w4 = *(const float4*)(wvbar + t * 4);
    ushort4 h, l;
    split2(x4.x, h.x, l.x); split2(x4.y, h.y, l.y);
    split2(x4.z, h.z, l.z); split2(x4.w, h.w, l.w);
    *(ushort4*)(Xhi + (size_t)row * EMBED + t * 4) = h;
    *(ushort4*)(Xlo + (size_t)row * EMBED + t * 4) = l;
    float s = x4.x * w4.x + x4.y * w4.y + x4.z * w4.z + x4.w * w4.w;
    float am = fmaxf(fmaxf(fabsf(x4.x), fabsf(x4.y)), fmaxf(fabsf(x4.z), fabsf(x4.w)));
    for (int d = 1; d < 64; d <<= 1) {
        s += __shfl_xor(s, d);
        am = fmaxf(am, __shfl_xor(am, d));
    }
    __shared__ float ws_[4], wa_[4];
    if ((t & 63) == 0) { ws_[t >> 6] = s; wa_[t >> 6] = am; }
    __syncthreads();
    if (t == 0) { vmean[row] = ws_[0] + ws_[1] + ws_[2] + ws_[3]; cnt[row] = 0; }
    if (X8) {
        float bm = fmaxf(fmaxf(wa_[0], wa_[1]), fmaxf(wa_[2], wa_[3]));
        bm = fmaxf(bm, 1e-20f);
        float inv = 127.0f / bm;
        char4 q;
        q.x = (signed char)(int)rintf(x4.x * inv);
        q.y = (signed char)(int)rintf(x4.y * inv);
        q.z = (signed char)(int)rintf(x4.z * inv);
        q.w = (signed char)(int)rintf(x4.w * inv);
        *(char4*)(X8 + (size_t)row * EMBED + t * 4) = q;
        if (t == 0) scaleX[row] = bm * (1.0f / 127.0f);
    }
}

// ---------------- prep: i8 row-quant of T (from Thi; scan only needs hi fidelity) ----------------
__global__ __launch_bounds__(256) void k_tquant(
    const unsigned short* __restrict__ Thi,
    signed char* __restrict__ T8, float* __restrict__ scaleT) {
    int row = blockIdx.x, t = threadIdx.x;
    ushort4 h = *(const ushort4*)(Thi + (size_t)row * EMBED + t * 4);
    float f0 = bf2f(h.x), f1 = bf2f(h.y), f2 = bf2f(h.z), f3 = bf2f(h.w);
    float am = fmaxf(fmaxf(fabsf(f0), fabsf(f1)), fmaxf(fabsf(f2), fabsf(f3)));
    for (int d = 1; d < 64; d <<= 1) am = fmaxf(am, __shfl_xor(am, d));
    __shared__ float wa_[4];
    if ((t & 63) == 0) wa_[t >> 6] = am;
    __syncthreads();
    float bm = fmaxf(fmaxf(fmaxf(wa_[0], wa_[1]), fmaxf(wa_[2], wa_[3])), 1e-20f);
    float inv = 127.0f / bm;
    char4 q;
    q.x = (signed char)(int)rintf(f0 * inv);
    q.y = (signed char)(int)rintf(f1 * inv);
    q.z = (signed char)(int)rintf(f2 * inv);
    q.w = (signed char)(int)rintf(f3 * inv);
    *(char4*)(T8 + (size_t)row * EMBED + t * 4) = q;
    if (t == 0) scaleT[row] = bm * (1.0f / 127.0f);
}

// ---------------- split-bf16 GEMM: C[row][col] = sum_k A[row][k]*B[col][k] (r4-proven) ----------------
__global__ __launch_bounds__(256) void k_gemm3(
    const unsigned short* __restrict__ Ahi, const unsigned short* __restrict__ Alo,
    const unsigned short* __restrict__ BThi, const unsigned short* __restrict__ BTlo,
    unsigned short* __restrict__ Chi, unsigned short* __restrict__ Clo) {
    __shared__ unsigned short Ah[128][32], Al[128][32], Bh[128][32], Bl[128][32];
    int bx = blockIdx.x;
    int bm = bx >> 3, bn = bx & 7;   // bn == XCD id under round-robin: B-tiles L2-local
    int tid = threadIdx.x, wave = tid >> 6, lane = tid & 63;
    int wm = (wave >> 1) * 64, wn = (wave & 1) * 64;
    int mrow = lane & 15, kq = (lane >> 4) * 8;

    f32x4 zero = {0.f, 0.f, 0.f, 0.f};
    f32x4 acc[4][4];
    for (int a = 0; a < 4; a++) for (int b = 0; b < 4; b++) acc[a][b] = zero;

    const unsigned short* Abase_h = Ahi + (size_t)(bm * 128) * EMBED;
    const unsigned short* Abase_l = Alo + (size_t)(bm * 128) * EMBED;
    const unsigned short* Bbase_h = BThi + (size_t)(bn * 128) * EMBED;
    const unsigned short* Bbase_l = BTlo + (size_t)(bn * 128) * EMBED;

    for (int k0 = 0; k0 < EMBED; k0 += 32) {
        __syncthreads();
        stage_tile(Ah, Abase_h + k0, wave, lane);
        stage_tile(Al, Abase_l + k0, wave, lane);
        stage_tile(Bh, Bbase_h + k0, wave, lane);
        stage_tile(Bl, Bbase_l + k0, wave, lane);
        __syncthreads();
        bf16x8 ah[4], al[4], bh[4], bl[4];
#pragma unroll
        for (int t = 0; t < 4; t++) {
            ah[t] = read_frag(Ah, wm + t * 16 + mrow, kq);
            al[t] = read_frag(Al, wm + t * 16 + mrow, kq);
            bh[t] = read_frag(Bh, wn + t * 16 + mrow, kq);
            bl[t] = read_frag(Bl, wn + t * 16 + mrow, kq);
        }
#pragma unroll
        for (int mt = 0; mt < 4; mt++)
#pragma unroll
            for (int nt = 0; nt < 4; nt++) {
                acc[mt][nt] = __builtin_amdgcn_mfma_f32_16x16x32_bf16(ah[mt], bh[nt], acc[mt][nt], 0, 0, 0);
                acc[mt][nt] = __builtin_amdgcn_mfma_f32_16x16x32_bf16(ah[mt], bl[nt], acc[mt][nt], 0, 0, 0);
                acc[mt][nt] = __builtin_amdgcn_mfma_f32_16x16x32_bf16(al[mt], bh[nt], acc[mt][nt], 0, 0, 0);
            }
    }
#pragma unroll
    for (int mt = 0; mt < 4; mt++)
#pragma unroll
        for (int nt = 0; nt < 4; nt++)
#pragma unroll
            for (int i = 0; i < 4; i++) {
                int row = bm * 128 + wm + mt * 16 + (lane >> 4) * 4 + i;
                int col = bn * 128 + wn + nt * 16 + (lane & 15);
                unsigned short h, l; split2(acc[mt][nt][i], h, l);
                Chi[(size_t)row * EMBED + col] = h;
                Clo[(size_t)row * EMBED + col] = l;
            }
}

// ---------------- scan (i8): 128q x 128k block, wave = 64q x 64k, r4 structure verbatim ----------------
// r13-r19 ledger: EIGHT schedule variants all land 215-250us, MfmaUtil pinned ~26%; per-CU
// accounting shows no pipe >50% busy -> latency-glued, schedule is not the lever at this
// shape. This round halves the WORK instead: i8 MFMA (16x16x64, 2x bf16 rate) halves MFMA
// issue, LDS bytes, staging, and FETCH. Capture-margin math: per-row quant noise sigma ~11
// scaled; TSCAN 50->140 and TRES 75->160 absorb 5*sqrt(2)*sigma while candidates/row ~45
// << CAP=128; rescore re-scores survivors EXACTLY in fp32, so output precision unchanged.
// Layout port is free: 128x64-i8 tile is byte-identical to the proven 128x32-short tile
// (4x16B segs/row, same swizzle, same 0-conflict pattern); i8 fragment kseg = lane>>4.
__global__ __launch_bounds__(256, 3) void k_scan(
    const signed char* __restrict__ T8, const signed char* __restrict__ X8,
    const float* __restrict__ scaleT, const float* __restrict__ scaleX,
    int* __restrict__ cnt, int2* __restrict__ cand) {
    __shared__ unsigned char ThA[128][64], KhA[128][64];
    __shared__ unsigned char ThB[128][64], KhB[128][64];   // BK=128 as two K=64 units (32 KB)
    __shared__ float rowmax_[2][2][64];
    __shared__ float sT_[128], sX_[128];
    int bid = blockIdx.x;            // 0..4095
    int x   = bid & 7;               // XCD id; each XCD owns 4 fixed 128-key tiles per batch
    int i   = bid >> 3;
    int kbi = i & 3;
    int qb  = (i >> 2) & 31;
    int b   = i >> 7;
    int kb  = x * 4 + kbi;
    int tid = threadIdx.x, wave = tid >> 6, lane = tid & 63;
    int wr = wave >> 1, wc = wave & 1;
    int wq = wr * 64, wk = wc * 64;
    int mrow = lane & 15, kseg = lane >> 4;
    size_t qrow0 = (size_t)b * SEQ + (size_t)qb * 128;
    size_t krow0 = (size_t)b * SEQ + (size_t)kb * 128;
    const unsigned char* Tk = (const unsigned char*)T8 + qrow0 * EMBED;
    const unsigned char* Xk = (const unsigned char*)X8 + krow0 * EMBED;

    if (tid < 128) sT_[tid] = scaleT[qrow0 + tid];
    else           sX_[tid - 128] = scaleX[krow0 + tid - 128];

    i32x4 zero = {0, 0, 0, 0};
    i32x4 acc[4][4];
    for (int a = 0; a < 4; a++) for (int c = 0; c < 4; c++) acc[a][c] = zero;

    for (int k0 = 0; k0 < EMBED; k0 += 128) {
        __syncthreads();
        stage_tile8(ThA, Tk + k0,      wave, lane);
        stage_tile8(KhA, Xk + k0,      wave, lane);
        stage_tile8(ThB, Tk + k0 + 64, wave, lane);
        stage_tile8(KhB, Xk + k0 + 64, wave, lane);
        __syncthreads();
        {   // unit A (k0 .. k0+63)
            i32x4 ah[4], bh[4];
#pragma unroll
            for (int t = 0; t < 4; t++) {
                ah[t] = read_frag8(ThA, wq + t * 16 + mrow, kseg);
                bh[t] = read_frag8(KhA, wk + t * 16 + mrow, kseg);
            }
#pragma unroll
            for (int mt = 0; mt < 4; mt++)
#pragma unroll
                for (int nt = 0; nt < 4; nt++)
                    acc[mt][nt] = __builtin_amdgcn_mfma_i32_16x16x64_i8(ah[mt], bh[nt], acc[mt][nt], 0, 0, 0);
        }
        {   // unit B (k0+64 .. k0+127)
            i32x4 ah[4], bh[4];
#pragma unroll
            for (int t = 0; t < 4; t++) {
                ah[t] = read_frag8(ThB, wq + t * 16 + mrow, kseg);
                bh[t] = read_frag8(KhB, wk + t * 16 + mrow, kseg);
            }
#pragma unroll
            for (int mt = 0; mt < 4; mt++)
#pragma unroll
                for (int nt = 0; nt < 4; nt++)
                    acc[mt][nt] = __builtin_amdgcn_mfma_i32_16x16x64_i8(ah[mt], bh[nt], acc[mt][nt], 0, 0, 0);
        }
    }

    // ---- epilogue pass 1: per-row max (scaled float) over this wave's 64 keys -> LDS ----
#pragma unroll
    for (int mt = 0; mt < 4; mt++)
#pragma unroll
        for (int i2 = 0; i2 < 4; i2++) {
            int lr = mt * 16 + (lane >> 4) * 4 + i2;
            float st = sT_[wq + lr] * 0.03125f;
            float v = -INFINITY;
#pragma unroll
            for (int nt = 0; nt < 4; nt++) {
                float sc = (float)acc[mt][nt][i2] * sX_[wk + nt * 16 + (lane & 15)];
                v = fmaxf(v, sc);
            }
            v *= st;   // st > 0: order preserved
#pragma unroll
            for (int d = 1; d < 16; d <<= 1) v = fmaxf(v, __shfl_xor(v, d));
            if ((lane & 15) == 0) rowmax_[wc][wr][lr] = v;
        }
    __syncthreads();
    // ---- epilogue pass 2: threshold over the block's FULL 128 keys; emit candidates ----
#pragma unroll
    for (int mt = 0; mt < 4; mt++)
#pragma unroll
        for (int i2 = 0; i2 < 4; i2++) {
            int lr = mt * 16 + (lane >> 4) * 4 + i2;
            float st = sT_[wq + lr] * 0.03125f;
            float th = fmaxf(rowmax_[0][wr][lr], rowmax_[1][wr][lr]) - TSCAN_SC;
            int grow = (int)qrow0 + wq + lr;
#pragma unroll
            for (int nt = 0; nt < 4; nt++) {
                float sc = (float)acc[mt][nt][i2] * sX_[wk + nt * 16 + (lane & 15)] * st;
                if (sc >= th) {
                    int gcol = (int)krow0 + wk + nt * 16 + (lane & 15);
                    int idx = atomicAdd(&cnt[grow], 1);
                    if (idx < CAP)
                        cand[(size_t)grow * CAP + idx] = make_int2(gcol, __float_as_int(sc));
                }
            }
        }
}

// ---------------- rescore: 4 rows per block, one wave per row, barrier-free ----------------
__global__ __launch_bounds__(256) void k_rescore(
    const unsigned short* __restrict__ Thi, const unsigned short* __restrict__ Tlo,
    const float* __restrict__ X, const float* __restrict__ vmean,
    const int* __restrict__ cnt, const int2* __restrict__ cand,
    float* __restrict__ out) {
    int wave = threadIdx.x >> 6, lane = threadIdx.x & 63;
    int row = blockIdx.x * 4 + wave;
    int c = cnt[row]; if (c > CAP) c = CAP;
    const int2* cl = cand + (size_t)row * CAP;

    float smax = -INFINITY;
    for (int j = lane; j < c; j += 64) smax = fmaxf(smax, __int_as_float(cl[j].y));
    for (int d = 1; d < 64; d <<= 1) smax = fmaxf(smax, __shfl_xor(smax, d));
    float th = smax - TRES;

    float q[16];
    {
        const unsigned short* qh = Thi + (size_t)row * EMBED + lane * 16;
        const unsigned short* ql = Tlo + (size_t)row * EMBED + lane * 16;
        bf16x8 h0 = *(const bf16x8*)qh, h1 = *(const bf16x8*)(qh + 8);
        bf16x8 l0 = *(const bf16x8*)ql, l1 = *(const bf16x8*)(ql + 8);
#pragma unroll
        for (int i = 0; i < 8; i++) {
            q[i]     = bf2f((unsigned short)h0[i]) + bf2f((unsigned short)l0[i]);
            q[i + 8] = bf2f((unsigned short)h1[i]) + bf2f((unsigned short)l1[i]);
        }
    }

    __shared__ int   sm_[4][CAP];
    __shared__ float sl_[4][CAP];
    __shared__ int   ns_[4];
    if (lane == 0) ns_[wave] = 0;
    for (int j = lane; j < c; j += 64) {
        int2 p = cl[j];
        if (__int_as_float(p.y) >= th) {
            int idx = atomicAdd(&ns_[wave], 1);
            sm_[wave][idx] = p.x;
        }
    }
    int ns = ns_[wave];
    for (int t = 0; t < ns; t++) {
        int m = sm_[wave][t];
        const float* xr = X + (size_t)m * EMBED + lane * 16;
        float4 a0 = *(const float4*)(xr);
        float4 a1 = *(const float4*)(xr + 4);
        float4 a2 = *(const float4*)(xr + 8);
        float4 a3 = *(const float4*)(xr + 12);
        float dp = q[0]*a0.x + q[1]*a0.y + q[2]*a0.z + q[3]*a0.w
                 + q[4]*a1.x + q[5]*a1.y + q[6]*a1.z + q[7]*a1.w
                 + q[8]*a2.x + q[9]*a2.y + q[10]*a2.z + q[11]*a2.w
                 + q[12]*a3.x + q[13]*a3.y + q[14]*a3.z + q[15]*a3.w;
        for (int d = 1; d < 64; d <<= 1) dp += __shfl_xor(dp, d);
        if (lane == 0) sl_[wave][t] = dp * 0.03125f;
    }
    if (lane == 0) {
        float lm = -INFINITY;
        for (int t = 0; t < ns; t++) lm = fmaxf(lm, sl_[wave][t]);
        float den = 0.f, num = 0.f;
        for (int t = 0; t < ns; t++) {
            float e = __expf(sl_[wave][t] - lm);
            den += e;
            num += e * vmean[sm_[wave][t]];
        }
        out[row] = num / den;
    }
}

extern "C" void kernel_launch(void* const* d_in, const int* in_sizes, int n_in,
                              void* d_out, int out_size, void* d_ws, size_t ws_size,
                              hipStream_t stream) {
    const float* X  = (const float*)d_in[0];
    const float* Wq = (const float*)d_in[1];
    const float* Wk = (const float*)d_in[2];
    const float* Wv = (const float*)d_in[3];
    float* out = (float*)d_out;

    char* p = (char*)d_ws;
    auto alloc = [&](size_t bytes) -> void* {
        void* q = (void*)p;
        p += (bytes + 255) & ~(size_t)255;
        return q;
    };
    unsigned short* Wqhi = (unsigned short*)alloc((size_t)EMBED * EMBED * 2);
    unsigned short* Wqlo = (unsigned short*)alloc((size_t)EMBED * EMBED * 2);
    unsigned short* Wkhi = (unsigned short*)alloc((size_t)EMBED * EMBED * 2);
    unsigned short* Wklo = (unsigned short*)alloc((size_t)EMBED * EMBED * 2);
    unsigned short* MThi = (unsigned short*)alloc((size_t)EMBED * EMBED * 2);
    unsigned short* MTlo = (unsigned short*)alloc((size_t)EMBED * EMBED * 2);
    unsigned short* Xhi  = (unsigned short*)alloc((size_t)ROWS * EMBED * 2);
    unsigned short* Xlo  = (unsigned short*)alloc((size_t)ROWS * EMBED * 2);
    unsigned short* Thi  = (unsigned short*)alloc((size_t)ROWS * EMBED * 2);
    unsigned short* Tlo  = (unsigned short*)alloc((size_t)ROWS * EMBED * 2);
    signed char*    T8   = (signed char*)alloc((size_t)ROWS * EMBED);
    signed char*    X8   = (signed char*)alloc((size_t)ROWS * EMBED);
    float* scaleT = (float*)alloc((size_t)ROWS * 4);
    float* scaleX = (float*)alloc((size_t)ROWS * 4);
    float* wvbar = (float*)alloc(EMBED * 4);
    float* vmean = (float*)alloc((size_t)ROWS * 4);
    int*   cnt   = (int*)alloc((size_t)ROWS * 4);
    int2*  cand  = (int2*)alloc((size_t)ROWS * CAP * 8);

    k_wvbar<<<EMBED, 256, 0, stream>>>(Wv, wvbar);
    // Row splits of the ORIGINAL Wq/Wk (no i8 quant for weights: X8=nullptr).
    k_xsplit_vmean<<<EMBED, 256, 0, stream>>>(Wq, wvbar, Wqhi, Wqlo, vmean, cnt, nullptr, nullptr);
    k_xsplit_vmean<<<EMBED, 256, 0, stream>>>(Wk, wvbar, Wkhi, Wklo, vmean, cnt, nullptr, nullptr);
    // M^T[b][a] = sum_n Wk[b][n]*Wq[a][n]
    k_gemm3<<<64, 256, 0, stream>>>(Wkhi, Wklo, Wqhi, Wqlo, MThi, MTlo);
    k_xsplit_vmean<<<ROWS, 256, 0, stream>>>(X, wvbar, Xhi, Xlo, vmean, cnt, X8, scaleX);  // real vmean+cnt=0+X8
    k_gemm3<<<1024, 256, 0, stream>>>(Xhi, Xlo, MThi, MTlo, Thi, Tlo);                     // T = X.M
    k_tquant<<<ROWS, 256, 0, stream>>>(Thi, T8, scaleT);                                   // T8 + scaleT
    k_scan<<<4096, 256, 0, stream>>>(T8, X8, scaleT, scaleX, cnt, cand);
    k_rescore<<<ROWS / 4, 256, 0, stream>>>(Thi, Tlo, X, vmean, cnt, cand, out);
}

// Round 9
// 473.299 us; speedup vs baseline: 1.1173x; 1.1173x over previous
//
#include <hip/hip_runtime.h>

#define EMBED 1024
#define BATCH 4
#define SEQ   4096
#define ROWS  (BATCH*SEQ)   // 16384
#define CAP   128           // candidate slots per row (r3-r12 proven)
#define TSCAN_U 1600.0f     // scan margin, unscaled (50 scaled) — r12-proven passing
#define TRES  75.0f         // rescore margin, scaled logits (proven)

typedef __attribute__((ext_vector_type(8))) short bf16x8;
typedef __attribute__((ext_vector_type(4))) float f32x4;

static __device__ __forceinline__ unsigned short f2bf(float x) {
    unsigned u = __float_as_uint(x);
    u = (u + 0x7fffu + ((u >> 16) & 1u)) >> 16;
    return (unsigned short)u;
}
static __device__ __forceinline__ float bf2f(unsigned short h) {
    return __uint_as_float(((unsigned)h) << 16);
}
static __device__ __forceinline__ void split2(float x, unsigned short& hi, unsigned short& lo) {
    hi = f2bf(x);
    lo = f2bf(x - bf2f(hi));
}

// ---- async global->LDS staging, 128x32-short tile, 4-segment swizzle (r3-proven, 0 conflicts) ----
static __device__ __forceinline__ void stage_tile(unsigned short (*lds)[32],
                                                  const unsigned short* gbase,
                                                  int wave, int lane) {
#pragma unroll
    for (int c = 0; c < 2; c++) {
        int L = wave * 128 + c * 64 + lane;   // linear segment index 0..511
        int r = L >> 2, s = L & 3;
        int g = (s - (r >> 1)) & 3;
        __builtin_amdgcn_global_load_lds(
            (const __attribute__((address_space(1))) unsigned int*)(gbase + (size_t)r * EMBED + g * 8),
            (__attribute__((address_space(3))) unsigned int*)(&lds[r][s * 8]),
            16, 0, 0);
    }
}
static __device__ __forceinline__ bf16x8 read_frag(const unsigned short (*lds)[32], int r, int kq) {
    int s = ((kq >> 3) + (r >> 1)) & 3;
    return *(const bf16x8*)&lds[r][s * 8];
}

// ---------------- prep: wv_bar[i] = mean_d Wv[i][d] ----------------
__global__ void k_wvbar(const float* __restrict__ Wv, float* __restrict__ wvbar) {
    int r = blockIdx.x, t = threadIdx.x;
    float s = 0.f;
    for (int c = t; c < EMBED; c += 256) s += Wv[(size_t)r * EMBED + c];
    for (int d = 1; d < 64; d <<= 1) s += __shfl_xor(s, d);
    __shared__ float ws_[4];
    if ((t & 63) == 0) ws_[t >> 6] = s;
    __syncthreads();
    if (t == 0) wvbar[r] = (ws_[0] + ws_[1] + ws_[2] + ws_[3]) * (1.0f / EMBED);
}

// ---------------- prep: row split + vmean + cnt zeroing (fused, one X read) ----------------
__global__ __launch_bounds__(256) void k_xsplit_vmean(
    const float* __restrict__ X, const float* __restrict__ wvbar,
    unsigned short* __restrict__ Xhi, unsigned short* __restrict__ Xlo,
    float* __restrict__ vmean, int* __restrict__ cnt) {
    int row = blockIdx.x, t = threadIdx.x;
    float4 x4 = *(const float4*)(X + (size_t)row * EMBED + t * 4);
    float4 w4 = *(const float4*)(wvbar + t * 4);
    ushort4 h, l;
    split2(x4.x, h.x, l.x); split2(x4.y, h.y, l.y);
    split2(x4.z, h.z, l.z); split2(x4.w, h.w, l.w);
    *(ushort4*)(Xhi + (size_t)row * EMBED + t * 4) = h;
    *(ushort4*)(Xlo + (size_t)row * EMBED + t * 4) = l;
    float s = x4.x * w4.x + x4.y * w4.y + x4.z * w4.z + x4.w * w4.w;
    for (int d = 1; d < 64; d <<= 1) s += __shfl_xor(s, d);
    __shared__ float ws_[4];
    if ((t & 63) == 0) ws_[t >> 6] = s;
    __syncthreads();
    if (t == 0) { vmean[row] = ws_[0] + ws_[1] + ws_[2] + ws_[3]; cnt[row] = 0; }
}

// ---------------- split-bf16 GEMM: C[row][col] = sum_k A[row][k]*B[col][k] (r4-proven) ----------------
__global__ __launch_bounds__(256) void k_gemm3(
    const unsigned short* __restrict__ Ahi, const unsigned short* __restrict__ Alo,
    const unsigned short* __restrict__ BThi, const unsigned short* __restrict__ BTlo,
    unsigned short* __restrict__ Chi, unsigned short* __restrict__ Clo) {
    __shared__ unsigned short Ah[128][32], Al[128][32], Bh[128][32], Bl[128][32];
    int bx = blockIdx.x;
    int bm = bx >> 3, bn = bx & 7;   // bn == XCD id under round-robin: B-tiles L2-local
    int tid = threadIdx.x, wave = tid >> 6, lane = tid & 63;
    int wm = (wave >> 1) * 64, wn = (wave & 1) * 64;
    int mrow = lane & 15, kq = (lane >> 4) * 8;

    f32x4 zero = {0.f, 0.f, 0.f, 0.f};
    f32x4 acc[4][4];
    for (int a = 0; a < 4; a++) for (int b = 0; b < 4; b++) acc[a][b] = zero;

    const unsigned short* Abase_h = Ahi + (size_t)(bm * 128) * EMBED;
    const unsigned short* Abase_l = Alo + (size_t)(bm * 128) * EMBED;
    const unsigned short* Bbase_h = BThi + (size_t)(bn * 128) * EMBED;
    const unsigned short* Bbase_l = BTlo + (size_t)(bn * 128) * EMBED;

    for (int k0 = 0; k0 < EMBED; k0 += 32) {
        __syncthreads();
        stage_tile(Ah, Abase_h + k0, wave, lane);
        stage_tile(Al, Abase_l + k0, wave, lane);
        stage_tile(Bh, Bbase_h + k0, wave, lane);
        stage_tile(Bl, Bbase_l + k0, wave, lane);
        __syncthreads();
        bf16x8 ah[4], al[4], bh[4], bl[4];
#pragma unroll
        for (int t = 0; t < 4; t++) {
            ah[t] = read_frag(Ah, wm + t * 16 + mrow, kq);
            al[t] = read_frag(Al, wm + t * 16 + mrow, kq);
            bh[t] = read_frag(Bh, wn + t * 16 + mrow, kq);
            bl[t] = read_frag(Bl, wn + t * 16 + mrow, kq);
        }
#pragma unroll
        for (int mt = 0; mt < 4; mt++)
#pragma unroll
            for (int nt = 0; nt < 4; nt++) {
                acc[mt][nt] = __builtin_amdgcn_mfma_f32_16x16x32_bf16(ah[mt], bh[nt], acc[mt][nt], 0, 0, 0);
                acc[mt][nt] = __builtin_amdgcn_mfma_f32_16x16x32_bf16(ah[mt], bl[nt], acc[mt][nt], 0, 0, 0);
                acc[mt][nt] = __builtin_amdgcn_mfma_f32_16x16x32_bf16(al[mt], bh[nt], acc[mt][nt], 0, 0, 0);
            }
    }
#pragma unroll
    for (int mt = 0; mt < 4; mt++)
#pragma unroll
        for (int nt = 0; nt < 4; nt++)
#pragma unroll
            for (int i = 0; i < 4; i++) {
                int row = bm * 128 + wm + mt * 16 + (lane >> 4) * 4 + i;
                int col = bn * 128 + wn + nt * 16 + (lane & 15);
                unsigned short h, l; split2(acc[mt][nt][i], h, l);
                Chi[(size_t)row * EMBED + col] = h;
                Clo[(size_t)row * EMBED + col] = l;
            }
}

// ---------------- scan: 128q x 128k block tile; each wave owns 64q x 64k (r4 loop verbatim) ----------------
// r13-r20 ledger: NINE loop/schedule/precision variants all land 215-250us; r19's i8 halved
// FLOPs+LDS+FETCH+iterations with ZERO wall change -> wall is work-independent. The one part
// never touched: the epilogue's per-hit returning atomicAdd(&cnt[row]). Per wave: ~384
// same-address atomics over rows spanning just 4 cache lines -> L2 atomic-unit serialization
// (~10-40K cy tails/wave, x32 blocks/row-line across XCDs) = the invariant wall. r21 fix:
// ballot-aggregated emission — ONE leader atomic per row per block (total via 4 group-mask
// popcounts), slots by prefix-popcount. Same capture set, disjoint slot ranges, rescore is
// order-insensitive -> semantics identical to r4.
__global__ __launch_bounds__(256, 3) void k_scan(
    const unsigned short* __restrict__ Thi, const unsigned short* __restrict__ Xhi,
    int* __restrict__ cnt, int2* __restrict__ cand) {
    __shared__ unsigned short ThA[128][32], KhA[128][32];
    __shared__ unsigned short ThB[128][32], KhB[128][32];   // BK=64 as two K=32 halves
    __shared__ float rowmax_[2][2][64];                     // [wc][wr][local row]
    int bid = blockIdx.x;            // 0..4095
    int x   = bid & 7;               // XCD id
    int i   = bid >> 3;              // 0..511
    int kbi = i & 3;                 // which of this XCD's 4 key tiles
    int qb  = (i >> 2) & 31;         // 128-row q tile
    int b   = i >> 7;                // batch
    int kb  = x * 4 + kbi;           // 0..31
    int tid = threadIdx.x, wave = tid >> 6, lane = tid & 63;
    int wr = wave >> 1, wc = wave & 1;
    int wq = wr * 64;                // q offset of this wave
    int wk = wc * 64;                // k offset of this wave
    int mrow = lane & 15, kq = (lane >> 4) * 8;
    size_t qrow0 = (size_t)b * SEQ + (size_t)qb * 128;
    size_t krow0 = (size_t)b * SEQ + (size_t)kb * 128;

    const unsigned short* Tbase = Thi + qrow0 * EMBED;
    const unsigned short* Xbase = Xhi + krow0 * EMBED;

    f32x4 zero = {0.f, 0.f, 0.f, 0.f};
    f32x4 acc[4][4];
    for (int a = 0; a < 4; a++) for (int c = 0; c < 4; c++) acc[a][c] = zero;

    for (int k0 = 0; k0 < EMBED; k0 += 64) {
        __syncthreads();
        stage_tile(ThA, Tbase + k0,      wave, lane);
        stage_tile(KhA, Xbase + k0,      wave, lane);
        stage_tile(ThB, Tbase + k0 + 32, wave, lane);
        stage_tile(KhB, Xbase + k0 + 32, wave, lane);
        __syncthreads();
        {   // sub-step A
            bf16x8 ah[4], bh[4];
#pragma unroll
            for (int t = 0; t < 4; t++) {
                ah[t] = read_frag(ThA, wq + t * 16 + mrow, kq);
                bh[t] = read_frag(KhA, wk + t * 16 + mrow, kq);
            }
#pragma unroll
            for (int mt = 0; mt < 4; mt++)
#pragma unroll
                for (int nt = 0; nt < 4; nt++)
                    acc[mt][nt] = __builtin_amdgcn_mfma_f32_16x16x32_bf16(ah[mt], bh[nt], acc[mt][nt], 0, 0, 0);
        }
        {   // sub-step B
            bf16x8 ah[4], bh[4];
#pragma unroll
            for (int t = 0; t < 4; t++) {
                ah[t] = read_frag(ThB, wq + t * 16 + mrow, kq);
                bh[t] = read_frag(KhB, wk + t * 16 + mrow, kq);
            }
#pragma unroll
            for (int mt = 0; mt < 4; mt++)
#pragma unroll
                for (int nt = 0; nt < 4; nt++)
                    acc[mt][nt] = __builtin_amdgcn_mfma_f32_16x16x32_bf16(ah[mt], bh[nt], acc[mt][nt], 0, 0, 0);
        }
    }

    // ---- epilogue pass 1: per-row max over this wave's 64 keys -> LDS exchange ----
#pragma unroll
    for (int mt = 0; mt < 4; mt++)
#pragma unroll
        for (int i2 = 0; i2 < 4; i2++) {
            float v = -INFINITY;
#pragma unroll
            for (int nt = 0; nt < 4; nt++) v = fmaxf(v, acc[mt][nt][i2]);
#pragma unroll
            for (int d = 1; d < 16; d <<= 1) v = fmaxf(v, __shfl_xor(v, d));
            if ((lane & 15) == 0) {
                int lr = mt * 16 + (lane >> 4) * 4 + i2;
                rowmax_[wc][wr][lr] = v;
            }
        }
    __syncthreads();
    // ---- epilogue pass 2: threshold over the block's FULL 128 keys; ballot-aggregated emit ----
    // One atomicAdd per row per block (leader of the row's 16-lane group); slots assigned by
    // prefix popcount over the 4 nt ballot masks. CAP truncation identical to per-hit version.
#pragma unroll
    for (int mt = 0; mt < 4; mt++)
#pragma unroll
        for (int i2 = 0; i2 < 4; i2++) {
            int lr = mt * 16 + (lane >> 4) * 4 + i2;
            float th = fmaxf(rowmax_[0][wr][lr], rowmax_[1][wr][lr]) - TSCAN_U;
            int grow = (int)qrow0 + wq + lr;
            int lpos = lane & 15;
            unsigned mm[4];
            float sc[4];
#pragma unroll
            for (int nt = 0; nt < 4; nt++) {
                sc[nt] = acc[mt][nt][i2];
                unsigned long long bal = __ballot(sc[nt] >= th);
                mm[nt] = (unsigned)((bal >> (lane & 48)) & 0xFFFFull);
            }
            int tot = __popc(mm[0]) + __popc(mm[1]) + __popc(mm[2]) + __popc(mm[3]);
            if (tot > 0) {                       // group-uniform branch (masks identical in group)
                int base = 0;
                if (lpos == 0) base = atomicAdd(&cnt[grow], tot);
                base = __shfl(base, lane & 48);  // broadcast from group leader
                int run = base;
                unsigned below = (1u << lpos) - 1u;
#pragma unroll
                for (int nt = 0; nt < 4; nt++) {
                    if (mm[nt] & (1u << lpos)) {
                        int slot = run + __popc(mm[nt] & below);
                        if (slot < CAP) {
                            int gcol = (int)krow0 + wk + nt * 16 + lpos;
                            cand[(size_t)grow * CAP + slot] =
                                make_int2(gcol, __float_as_int(sc[nt] * 0.03125f));
                        }
                    }
                    run += __popc(mm[nt]);
                }
            }
        }
}

// ---------------- rescore: 4 rows per block, one wave per row, barrier-free ----------------
__global__ __launch_bounds__(256) void k_rescore(
    const unsigned short* __restrict__ Thi, const unsigned short* __restrict__ Tlo,
    const float* __restrict__ X, const float* __restrict__ vmean,
    const int* __restrict__ cnt, const int2* __restrict__ cand,
    float* __restrict__ out) {
    int wave = threadIdx.x >> 6, lane = threadIdx.x & 63;
    int row = blockIdx.x * 4 + wave;
    int c = cnt[row]; if (c > CAP) c = CAP;
    const int2* cl = cand + (size_t)row * CAP;

    float smax = -INFINITY;
    for (int j = lane; j < c; j += 64) smax = fmaxf(smax, __int_as_float(cl[j].y));
    for (int d = 1; d < 64; d <<= 1) smax = fmaxf(smax, __shfl_xor(smax, d));
    float th = smax - TRES;

    float q[16];
    {
        const unsigned short* qh = Thi + (size_t)row * EMBED + lane * 16;
        const unsigned short* ql = Tlo + (size_t)row * EMBED + lane * 16;
        bf16x8 h0 = *(const bf16x8*)qh, h1 = *(const bf16x8*)(qh + 8);
        bf16x8 l0 = *(const bf16x8*)ql, l1 = *(const bf16x8*)(ql + 8);
#pragma unroll
        for (int i = 0; i < 8; i++) {
            q[i]     = bf2f((unsigned short)h0[i]) + bf2f((unsigned short)l0[i]);
            q[i + 8] = bf2f((unsigned short)h1[i]) + bf2f((unsigned short)l1[i]);
        }
    }

    __shared__ int   sm_[4][CAP];
    __shared__ float sl_[4][CAP];
    __shared__ int   ns_[4];
    if (lane == 0) ns_[wave] = 0;
    for (int j = lane; j < c; j += 64) {
        int2 p = cl[j];
        if (__int_as_float(p.y) >= th) {
            int idx = atomicAdd(&ns_[wave], 1);
            sm_[wave][idx] = p.x;
        }
    }
    int ns = ns_[wave];
    for (int t = 0; t < ns; t++) {
        int m = sm_[wave][t];
        const float* xr = X + (size_t)m * EMBED + lane * 16;
        float4 a0 = *(const float4*)(xr);
        float4 a1 = *(const float4*)(xr + 4);
        float4 a2 = *(const float4*)(xr + 8);
        float4 a3 = *(const float4*)(xr + 12);
        float dp = q[0]*a0.x + q[1]*a0.y + q[2]*a0.z + q[3]*a0.w
                 + q[4]*a1.x + q[5]*a1.y + q[6]*a1.z + q[7]*a1.w
                 + q[8]*a2.x + q[9]*a2.y + q[10]*a2.z + q[11]*a2.w
                 + q[12]*a3.x + q[13]*a3.y + q[14]*a3.z + q[15]*a3.w;
        for (int d = 1; d < 64; d <<= 1) dp += __shfl_xor(dp, d);
        if (lane == 0) sl_[wave][t] = dp * 0.03125f;
    }
    if (lane == 0) {
        float lm = -INFINITY;
        for (int t = 0; t < ns; t++) lm = fmaxf(lm, sl_[wave][t]);
        float den = 0.f, num = 0.f;
        for (int t = 0; t < ns; t++) {
            float e = __expf(sl_[wave][t] - lm);
            den += e;
            num += e * vmean[sm_[wave][t]];
        }
        out[row] = num / den;
    }
}

extern "C" void kernel_launch(void* const* d_in, const int* in_sizes, int n_in,
                              void* d_out, int out_size, void* d_ws, size_t ws_size,
                              hipStream_t stream) {
    const float* X  = (const float*)d_in[0];
    const float* Wq = (const float*)d_in[1];
    const float* Wk = (const float*)d_in[2];
    const float* Wv = (const float*)d_in[3];
    float* out = (float*)d_out;

    char* p = (char*)d_ws;
    auto alloc = [&](size_t bytes) -> void* {
        void* q = (void*)p;
        p += (bytes + 255) & ~(size_t)255;
        return q;
    };
    unsigned short* Wqhi = (unsigned short*)alloc((size_t)EMBED * EMBED * 2);
    unsigned short* Wqlo = (unsigned short*)alloc((size_t)EMBED * EMBED * 2);
    unsigned short* Wkhi = (unsigned short*)alloc((size_t)EMBED * EMBED * 2);
    unsigned short* Wklo = (unsigned short*)alloc((size_t)EMBED * EMBED * 2);
    unsigned short* MThi = (unsigned short*)alloc((size_t)EMBED * EMBED * 2);
    unsigned short* MTlo = (unsigned short*)alloc((size_t)EMBED * EMBED * 2);
    unsigned short* Xhi  = (unsigned short*)alloc((size_t)ROWS * EMBED * 2);
    unsigned short* Xlo  = (unsigned short*)alloc((size_t)ROWS * EMBED * 2);
    unsigned short* Thi  = (unsigned short*)alloc((size_t)ROWS * EMBED * 2);
    unsigned short* Tlo  = (unsigned short*)alloc((size_t)ROWS * EMBED * 2);
    float* wvbar = (float*)alloc(EMBED * 4);
    float* vmean = (float*)alloc((size_t)ROWS * 4);
    int*   cnt   = (int*)alloc((size_t)ROWS * 4);
    int2*  cand  = (int2*)alloc((size_t)ROWS * CAP * 8);

    k_wvbar<<<EMBED, 256, 0, stream>>>(Wv, wvbar);
    // Row splits of the ORIGINAL Wq/Wk (M contraction is over the contiguous output dim).
    // vmean/cnt args are scratch here (rows 0..1023; real run below overwrites all rows).
    k_xsplit_vmean<<<EMBED, 256, 0, stream>>>(Wq, wvbar, Wqhi, Wqlo, vmean, cnt);
    k_xsplit_vmean<<<EMBED, 256, 0, stream>>>(Wk, wvbar, Wkhi, Wklo, vmean, cnt);
    // M^T[b][a] = sum_n Wk[b][n]*Wq[a][n]
    k_gemm3<<<64, 256, 0, stream>>>(Wkhi, Wklo, Wqhi, Wqlo, MThi, MTlo);
    k_xsplit_vmean<<<ROWS, 256, 0, stream>>>(X, wvbar, Xhi, Xlo, vmean, cnt);  // real vmean + cnt=0
    k_gemm3<<<1024, 256, 0, stream>>>(Xhi, Xlo, MThi, MTlo, Thi, Tlo);         // T = X.M
    k_scan<<<4096, 256, 0, stream>>>(Thi, Xhi, cnt, cand);
    k_rescore<<<ROWS / 4, 256, 0, stream>>>(Thi, Tlo, X, vmean, cnt, cand, out);
}

// Round 10
// 463.988 us; speedup vs baseline: 1.1397x; 1.0201x over previous
//
#include <hip/hip_runtime.h>

#define EMBED 1024
#define BATCH 4
#define SEQ   4096
#define ROWS  (BATCH*SEQ)   // 16384
#define CAP   128           // candidate slots per row (r3-r12 proven)
#define TSCAN_SC 140.0f     // scan margin, SCALED: 50 (proven) + 5*sqrt(2)*sigma_q (r8-proven)
#define TRES  160.0f        // rescore margin, scaled: 75 (proven) + i8 noise allowance (r8-proven)

typedef __attribute__((ext_vector_type(8))) short bf16x8;
typedef __attribute__((ext_vector_type(4))) float f32x4;
typedef __attribute__((ext_vector_type(4))) int   i32x4;

static __device__ __forceinline__ unsigned short f2bf(float x) {
    unsigned u = __float_as_uint(x);
    u = (u + 0x7fffu + ((u >> 16) & 1u)) >> 16;
    return (unsigned short)u;
}
static __device__ __forceinline__ float bf2f(unsigned short h) {
    return __uint_as_float(((unsigned)h) << 16);
}
static __device__ __forceinline__ void split2(float x, unsigned short& hi, unsigned short& lo) {
    hi = f2bf(x);
    lo = f2bf(x - bf2f(hi));
}

// ---- async global->LDS, one 16B segment ----
static __device__ __forceinline__ void gll(const unsigned short* g, unsigned short* l) {
    __builtin_amdgcn_global_load_lds(
        (const __attribute__((address_space(1))) unsigned int*)g,
        (__attribute__((address_space(3))) unsigned int*)l, 16, 0, 0);
}
static __device__ __forceinline__ void gllb(const unsigned char* g, unsigned char* l) {
    __builtin_amdgcn_global_load_lds(
        (const __attribute__((address_space(1))) unsigned int*)g,
        (__attribute__((address_space(3))) unsigned int*)l, 16, 0, 0);
}
// ---- 128x32-short tile stager, 4-segment swizzle (r3-proven, 0 conflicts) ----
static __device__ __forceinline__ void stage_tile(unsigned short (*lds)[32],
                                                  const unsigned short* gbase,
                                                  int wave, int lane) {
#pragma unroll
    for (int c = 0; c < 2; c++) {
        int L = wave * 128 + c * 64 + lane;
        int r = L >> 2, s = L & 3;
        int g = (s - (r >> 1)) & 3;
        gll(gbase + (size_t)r * EMBED + g * 8, &lds[r][s * 8]);
    }
}
static __device__ __forceinline__ bf16x8 read_frag(const unsigned short (*lds)[32], int r, int kq) {
    int s = ((kq >> 3) + (r >> 1)) & 3;
    return *(const bf16x8*)&lds[r][s * 8];
}
// ---- byte-identical i8 variants: 128 rows x 64 i8 = 4 x 16B segs/row, same swizzle (r8-proven) ----
static __device__ __forceinline__ void stage_tile8(unsigned char (*lds)[64],
                                                   const unsigned char* gbase,
                                                   int wave, int lane) {
#pragma unroll
    for (int c = 0; c < 2; c++) {
        int L = wave * 128 + c * 64 + lane;
        int r = L >> 2, s = L & 3;
        int g = (s - (r >> 1)) & 3;
        gllb(gbase + (size_t)r * EMBED + g * 16, &lds[r][s * 16]);
    }
}
static __device__ __forceinline__ i32x4 read_frag8(const unsigned char (*lds)[64], int r, int kseg) {
    int s = (kseg + (r >> 1)) & 3;
    return *(const i32x4*)&lds[r][s * 16];
}

// ---------------- prep: wv_bar[i] = mean_d Wv[i][d] ----------------
__global__ void k_wvbar(const float* __restrict__ Wv, float* __restrict__ wvbar) {
    int r = blockIdx.x, t = threadIdx.x;
    float s = 0.f;
    for (int c = t; c < EMBED; c += 256) s += Wv[(size_t)r * EMBED + c];
    for (int d = 1; d < 64; d <<= 1) s += __shfl_xor(s, d);
    __shared__ float ws_[4];
    if ((t & 63) == 0) ws_[t >> 6] = s;
    __syncthreads();
    if (t == 0) wvbar[r] = (ws_[0] + ws_[1] + ws_[2] + ws_[3]) * (1.0f / EMBED);
}

// ---------------- prep: row split + vmean + cnt zero + (optional) i8 row-quant of X ----------------
__global__ __launch_bounds__(256) void k_xsplit_vmean(
    const float* __restrict__ X, const float* __restrict__ wvbar,
    unsigned short* __restrict__ Xhi, unsigned short* __restrict__ Xlo,
    float* __restrict__ vmean, int* __restrict__ cnt,
    signed char* __restrict__ X8, float* __restrict__ scaleX) {
    int row = blockIdx.x, t = threadIdx.x;
    float4 x4 = *(const float4*)(X + (size_t)row * EMBED + t * 4);
    float4 w4 = *(const float4*)(wvbar + t * 4);
    ushort4 h, l;
    split2(x4.x, h.x, l.x); split2(x4.y, h.y, l.y);
    split2(x4.z, h.z, l.z); split2(x4.w, h.w, l.w);
    *(ushort4*)(Xhi + (size_t)row * EMBED + t * 4) = h;
    *(ushort4*)(Xlo + (size_t)row * EMBED + t * 4) = l;
    float s = x4.x * w4.x + x4.y * w4.y + x4.z * w4.z + x4.w * w4.w;
    float am = fmaxf(fmaxf(fabsf(x4.x), fabsf(x4.y)), fmaxf(fabsf(x4.z), fabsf(x4.w)));
    for (int d = 1; d < 64; d <<= 1) {
        s += __shfl_xor(s, d);
        am = fmaxf(am, __shfl_xor(am, d));
    }
    __shared__ float ws_[4], wa_[4];
    if ((t & 63) == 0) { ws_[t >> 6] = s; wa_[t >> 6] = am; }
    __syncthreads();
    if (t == 0) { vmean[row] = ws_[0] + ws_[1] + ws_[2] + ws_[3]; cnt[row] = 0; }
    if (X8) {
        float bm = fmaxf(fmaxf(wa_[0], wa_[1]), fmaxf(wa_[2], wa_[3]));
        bm = fmaxf(bm, 1e-20f);
        float inv = 127.0f / bm;
        char4 q;
        q.x = (signed char)(int)rintf(x4.x * inv);
        q.y = (signed char)(int)rintf(x4.y * inv);
        q.z = (signed char)(int)rintf(x4.z * inv);
        q.w = (signed char)(int)rintf(x4.w * inv);
        *(char4*)(X8 + (size_t)row * EMBED + t * 4) = q;
        if (t == 0) scaleX[row] = bm * (1.0f / 127.0f);
    }
}

// ---------------- prep: i8 row-quant of T (from Thi; scan only needs hi fidelity) ----------------
__global__ __launch_bounds__(256) void k_tquant(
    const unsigned short* __restrict__ Thi,
    signed char* __restrict__ T8, float* __restrict__ scaleT) {
    int row = blockIdx.x, t = threadIdx.x;
    ushort4 h = *(const ushort4*)(Thi + (size_t)row * EMBED + t * 4);
    float f0 = bf2f(h.x), f1 = bf2f(h.y), f2 = bf2f(h.z), f3 = bf2f(h.w);
    float am = fmaxf(fmaxf(fabsf(f0), fabsf(f1)), fmaxf(fabsf(f2), fabsf(f3)));
    for (int d = 1; d < 64; d <<= 1) am = fmaxf(am, __shfl_xor(am, d));
    __shared__ float wa_[4];
    if ((t & 63) == 0) wa_[t >> 6] = am;
    __syncthreads();
    float bm = fmaxf(fmaxf(fmaxf(wa_[0], wa_[1]), fmaxf(wa_[2], wa_[3])), 1e-20f);
    float inv = 127.0f / bm;
    char4 q;
    q.x = (signed char)(int)rintf(f0 * inv);
    q.y = (signed char)(int)rintf(f1 * inv);
    q.z = (signed char)(int)rintf(f2 * inv);
    q.w = (signed char)(int)rintf(f3 * inv);
    *(char4*)(T8 + (size_t)row * EMBED + t * 4) = q;
    if (t == 0) scaleT[row] = bm * (1.0f / 127.0f);
}

// ---------------- split-bf16 GEMM: C[row][col] = sum_k A[row][k]*B[col][k] (r4-proven) ----------------
__global__ __launch_bounds__(256) void k_gemm3(
    const unsigned short* __restrict__ Ahi, const unsigned short* __restrict__ Alo,
    const unsigned short* __restrict__ BThi, const unsigned short* __restrict__ BTlo,
    unsigned short* __restrict__ Chi, unsigned short* __restrict__ Clo) {
    __shared__ unsigned short Ah[128][32], Al[128][32], Bh[128][32], Bl[128][32];
    int bx = blockIdx.x;
    int bm = bx >> 3, bn = bx & 7;   // bn == XCD id under round-robin: B-tiles L2-local
    int tid = threadIdx.x, wave = tid >> 6, lane = tid & 63;
    int wm = (wave >> 1) * 64, wn = (wave & 1) * 64;
    int mrow = lane & 15, kq = (lane >> 4) * 8;

    f32x4 zero = {0.f, 0.f, 0.f, 0.f};
    f32x4 acc[4][4];
    for (int a = 0; a < 4; a++) for (int b = 0; b < 4; b++) acc[a][b] = zero;

    const unsigned short* Abase_h = Ahi + (size_t)(bm * 128) * EMBED;
    const unsigned short* Abase_l = Alo + (size_t)(bm * 128) * EMBED;
    const unsigned short* Bbase_h = BThi + (size_t)(bn * 128) * EMBED;
    const unsigned short* Bbase_l = BTlo + (size_t)(bn * 128) * EMBED;

    for (int k0 = 0; k0 < EMBED; k0 += 32) {
        __syncthreads();
        stage_tile(Ah, Abase_h + k0, wave, lane);
        stage_tile(Al, Abase_l + k0, wave, lane);
        stage_tile(Bh, Bbase_h + k0, wave, lane);
        stage_tile(Bl, Bbase_l + k0, wave, lane);
        __syncthreads();
        bf16x8 ah[4], al[4], bh[4], bl[4];
#pragma unroll
        for (int t = 0; t < 4; t++) {
            ah[t] = read_frag(Ah, wm + t * 16 + mrow, kq);
            al[t] = read_frag(Al, wm + t * 16 + mrow, kq);
            bh[t] = read_frag(Bh, wn + t * 16 + mrow, kq);
            bl[t] = read_frag(Bl, wn + t * 16 + mrow, kq);
        }
#pragma unroll
        for (int mt = 0; mt < 4; mt++)
#pragma unroll
            for (int nt = 0; nt < 4; nt++) {
                acc[mt][nt] = __builtin_amdgcn_mfma_f32_16x16x32_bf16(ah[mt], bh[nt], acc[mt][nt], 0, 0, 0);
                acc[mt][nt] = __builtin_amdgcn_mfma_f32_16x16x32_bf16(ah[mt], bl[nt], acc[mt][nt], 0, 0, 0);
                acc[mt][nt] = __builtin_amdgcn_mfma_f32_16x16x32_bf16(al[mt], bh[nt], acc[mt][nt], 0, 0, 0);
            }
    }
#pragma unroll
    for (int mt = 0; mt < 4; mt++)
#pragma unroll
        for (int nt = 0; nt < 4; nt++)
#pragma unroll
            for (int i = 0; i < 4; i++) {
                int row = bm * 128 + wm + mt * 16 + (lane >> 4) * 4 + i;
                int col = bn * 128 + wn + nt * 16 + (lane & 15);
                unsigned short h, l; split2(acc[mt][nt][i], h, l);
                Chi[(size_t)row * EMBED + col] = h;
                Clo[(size_t)row * EMBED + col] = l;
            }
}

// ---------------- scan: i8 loop (r8-proven) + ballot epilogue (r9-proven) ----------------
// r21 showed the invariant wall was the per-hit returning atomicAdd (ballot fix: 215->191).
// r19's i8 null (half MFMA, half intervals, half staging -> zero wall change) was measured
// BEHIND that wall: wall = max(loop, atomic-tail). With the wall gone the loop (~150 of
// 191us) is binding again, so i8's halving gets its legitimate test now. Margins r8-proven
// (TSCAN_SC=140, TRES=160, passed absmax unchanged); rescore re-scores survivors EXACTLY
// in fp32 so output precision is untouched. Tile layout byte-identical to bf16 (0-conflict).
__global__ __launch_bounds__(256, 3) void k_scan(
    const signed char* __restrict__ T8, const signed char* __restrict__ X8,
    const float* __restrict__ scaleT, const float* __restrict__ scaleX,
    int* __restrict__ cnt, int2* __restrict__ cand) {
    __shared__ unsigned char ThA[128][64], KhA[128][64];
    __shared__ unsigned char ThB[128][64], KhB[128][64];   // BK=128 as two K=64 units (32 KB)
    __shared__ float rowmax_[2][2][64];
    __shared__ float sT_[128], sX_[128];
    int bid = blockIdx.x;            // 0..4095
    int x   = bid & 7;               // XCD id; each XCD owns 4 fixed 128-key tiles per batch
    int i   = bid >> 3;
    int kbi = i & 3;
    int qb  = (i >> 2) & 31;
    int b   = i >> 7;
    int kb  = x * 4 + kbi;
    int tid = threadIdx.x, wave = tid >> 6, lane = tid & 63;
    int wr = wave >> 1, wc = wave & 1;
    int wq = wr * 64, wk = wc * 64;
    int mrow = lane & 15, kseg = lane >> 4;
    size_t qrow0 = (size_t)b * SEQ + (size_t)qb * 128;
    size_t krow0 = (size_t)b * SEQ + (size_t)kb * 128;
    const unsigned char* Tk = (const unsigned char*)T8 + qrow0 * EMBED;
    const unsigned char* Xk = (const unsigned char*)X8 + krow0 * EMBED;

    if (tid < 128) sT_[tid] = scaleT[qrow0 + tid];
    else           sX_[tid - 128] = scaleX[krow0 + tid - 128];

    i32x4 zero = {0, 0, 0, 0};
    i32x4 acc[4][4];
    for (int a = 0; a < 4; a++) for (int c = 0; c < 4; c++) acc[a][c] = zero;

    for (int k0 = 0; k0 < EMBED; k0 += 128) {
        __syncthreads();
        stage_tile8(ThA, Tk + k0,      wave, lane);
        stage_tile8(KhA, Xk + k0,      wave, lane);
        stage_tile8(ThB, Tk + k0 + 64, wave, lane);
        stage_tile8(KhB, Xk + k0 + 64, wave, lane);
        __syncthreads();
        {   // unit A (k0 .. k0+63)
            i32x4 ah[4], bh[4];
#pragma unroll
            for (int t = 0; t < 4; t++) {
                ah[t] = read_frag8(ThA, wq + t * 16 + mrow, kseg);
                bh[t] = read_frag8(KhA, wk + t * 16 + mrow, kseg);
            }
#pragma unroll
            for (int mt = 0; mt < 4; mt++)
#pragma unroll
                for (int nt = 0; nt < 4; nt++)
                    acc[mt][nt] = __builtin_amdgcn_mfma_i32_16x16x64_i8(ah[mt], bh[nt], acc[mt][nt], 0, 0, 0);
        }
        {   // unit B (k0+64 .. k0+127)
            i32x4 ah[4], bh[4];
#pragma unroll
            for (int t = 0; t < 4; t++) {
                ah[t] = read_frag8(ThB, wq + t * 16 + mrow, kseg);
                bh[t] = read_frag8(KhB, wk + t * 16 + mrow, kseg);
            }
#pragma unroll
            for (int mt = 0; mt < 4; mt++)
#pragma unroll
                for (int nt = 0; nt < 4; nt++)
                    acc[mt][nt] = __builtin_amdgcn_mfma_i32_16x16x64_i8(ah[mt], bh[nt], acc[mt][nt], 0, 0, 0);
        }
    }

    // ---- epilogue pass 1: per-row max (scaled float) over this wave's 64 keys -> LDS ----
#pragma unroll
    for (int mt = 0; mt < 4; mt++)
#pragma unroll
        for (int i2 = 0; i2 < 4; i2++) {
            int lr = mt * 16 + (lane >> 4) * 4 + i2;
            float st = sT_[wq + lr] * 0.03125f;
            float v = -INFINITY;
#pragma unroll
            for (int nt = 0; nt < 4; nt++) {
                float sc = (float)acc[mt][nt][i2] * sX_[wk + nt * 16 + (lane & 15)];
                v = fmaxf(v, sc);
            }
            v *= st;   // st > 0: order preserved
#pragma unroll
            for (int d = 1; d < 16; d <<= 1) v = fmaxf(v, __shfl_xor(v, d));
            if ((lane & 15) == 0) rowmax_[wc][wr][lr] = v;
        }
    __syncthreads();
    // ---- epilogue pass 2: threshold over the block's FULL 128 keys; ballot-aggregated emit ----
    // One atomicAdd per row per block (group leader); slots by prefix popcount (r9-proven).
#pragma unroll
    for (int mt = 0; mt < 4; mt++)
#pragma unroll
        for (int i2 = 0; i2 < 4; i2++) {
            int lr = mt * 16 + (lane >> 4) * 4 + i2;
            float st = sT_[wq + lr] * 0.03125f;
            float th = fmaxf(rowmax_[0][wr][lr], rowmax_[1][wr][lr]) - TSCAN_SC;
            int grow = (int)qrow0 + wq + lr;
            int lpos = lane & 15;
            unsigned mm[4];
            float sc[4];
#pragma unroll
            for (int nt = 0; nt < 4; nt++) {
                sc[nt] = (float)acc[mt][nt][i2] * sX_[wk + nt * 16 + lpos] * st;
                unsigned long long bal = __ballot(sc[nt] >= th);
                mm[nt] = (unsigned)((bal >> (lane & 48)) & 0xFFFFull);
            }
            int tot = __popc(mm[0]) + __popc(mm[1]) + __popc(mm[2]) + __popc(mm[3]);
            if (tot > 0) {                       // group-uniform branch
                int base = 0;
                if (lpos == 0) base = atomicAdd(&cnt[grow], tot);
                base = __shfl(base, lane & 48);  // broadcast from group leader
                int run = base;
                unsigned below = (1u << lpos) - 1u;
#pragma unroll
                for (int nt = 0; nt < 4; nt++) {
                    if (mm[nt] & (1u << lpos)) {
                        int slot = run + __popc(mm[nt] & below);
                        if (slot < CAP) {
                            int gcol = (int)krow0 + wk + nt * 16 + lpos;
                            cand[(size_t)grow * CAP + slot] =
                                make_int2(gcol, __float_as_int(sc[nt]));
                        }
                    }
                    run += __popc(mm[nt]);
                }
            }
        }
}

// ---------------- rescore: 4 rows per block, one wave per row, barrier-free ----------------
__global__ __launch_bounds__(256) void k_rescore(
    const unsigned short* __restrict__ Thi, const unsigned short* __restrict__ Tlo,
    const float* __restrict__ X, const float* __restrict__ vmean,
    const int* __restrict__ cnt, const int2* __restrict__ cand,
    float* __restrict__ out) {
    int wave = threadIdx.x >> 6, lane = threadIdx.x & 63;
    int row = blockIdx.x * 4 + wave;
    int c = cnt[row]; if (c > CAP) c = CAP;
    const int2* cl = cand + (size_t)row * CAP;

    float smax = -INFINITY;
    for (int j = lane; j < c; j += 64) smax = fmaxf(smax, __int_as_float(cl[j].y));
    for (int d = 1; d < 64; d <<= 1) smax = fmaxf(smax, __shfl_xor(smax, d));
    float th = smax - TRES;

    float q[16];
    {
        const unsigned short* qh = Thi + (size_t)row * EMBED + lane * 16;
        const unsigned short* ql = Tlo + (size_t)row * EMBED + lane * 16;
        bf16x8 h0 = *(const bf16x8*)qh, h1 = *(const bf16x8*)(qh + 8);
        bf16x8 l0 = *(const bf16x8*)ql, l1 = *(const bf16x8*)(ql + 8);
#pragma unroll
        for (int i = 0; i < 8; i++) {
            q[i]     = bf2f((unsigned short)h0[i]) + bf2f((unsigned short)l0[i]);
            q[i + 8] = bf2f((unsigned short)h1[i]) + bf2f((unsigned short)l1[i]);
        }
    }

    __shared__ int   sm_[4][CAP];
    __shared__ float sl_[4][CAP];
    __shared__ int   ns_[4];
    if (lane == 0) ns_[wave] = 0;
    for (int j = lane; j < c; j += 64) {
        int2 p = cl[j];
        if (__int_as_float(p.y) >= th) {
            int idx = atomicAdd(&ns_[wave], 1);
            sm_[wave][idx] = p.x;
        }
    }
    int ns = ns_[wave];
    for (int t = 0; t < ns; t++) {
        int m = sm_[wave][t];
        const float* xr = X + (size_t)m * EMBED + lane * 16;
        float4 a0 = *(const float4*)(xr);
        float4 a1 = *(const float4*)(xr + 4);
        float4 a2 = *(const float4*)(xr + 8);
        float4 a3 = *(const float4*)(xr + 12);
        float dp = q[0]*a0.x + q[1]*a0.y + q[2]*a0.z + q[3]*a0.w
                 + q[4]*a1.x + q[5]*a1.y + q[6]*a1.z + q[7]*a1.w
                 + q[8]*a2.x + q[9]*a2.y + q[10]*a2.z + q[11]*a2.w
                 + q[12]*a3.x + q[13]*a3.y + q[14]*a3.z + q[15]*a3.w;
        for (int d = 1; d < 64; d <<= 1) dp += __shfl_xor(dp, d);
        if (lane == 0) sl_[wave][t] = dp * 0.03125f;
    }
    if (lane == 0) {
        float lm = -INFINITY;
        for (int t = 0; t < ns; t++) lm = fmaxf(lm, sl_[wave][t]);
        float den = 0.f, num = 0.f;
        for (int t = 0; t < ns; t++) {
            float e = __expf(sl_[wave][t] - lm);
            den += e;
            num += e * vmean[sm_[wave][t]];
        }
        out[row] = num / den;
    }
}

extern "C" void kernel_launch(void* const* d_in, const int* in_sizes, int n_in,
                              void* d_out, int out_size, void* d_ws, size_t ws_size,
                              hipStream_t stream) {
    const float* X  = (const float*)d_in[0];
    const float* Wq = (const float*)d_in[1];
    const float* Wk = (const float*)d_in[2];
    const float* Wv = (const float*)d_in[3];
    float* out = (float*)d_out;

    char* p = (char*)d_ws;
    auto alloc = [&](size_t bytes) -> void* {
        void* q = (void*)p;
        p += (bytes + 255) & ~(size_t)255;
        return q;
    };
    unsigned short* Wqhi = (unsigned short*)alloc((size_t)EMBED * EMBED * 2);
    unsigned short* Wqlo = (unsigned short*)alloc((size_t)EMBED * EMBED * 2);
    unsigned short* Wkhi = (unsigned short*)alloc((size_t)EMBED * EMBED * 2);
    unsigned short* Wklo = (unsigned short*)alloc((size_t)EMBED * EMBED * 2);
    unsigned short* MThi = (unsigned short*)alloc((size_t)EMBED * EMBED * 2);
    unsigned short* MTlo = (unsigned short*)alloc((size_t)EMBED * EMBED * 2);
    unsigned short* Xhi  = (unsigned short*)alloc((size_t)ROWS * EMBED * 2);
    unsigned short* Xlo  = (unsigned short*)alloc((size_t)ROWS * EMBED * 2);
    unsigned short* Thi  = (unsigned short*)alloc((size_t)ROWS * EMBED * 2);
    unsigned short* Tlo  = (unsigned short*)alloc((size_t)ROWS * EMBED * 2);
    signed char*    T8   = (signed char*)alloc((size_t)ROWS * EMBED);
    signed char*    X8   = (signed char*)alloc((size_t)ROWS * EMBED);
    float* scaleT = (float*)alloc((size_t)ROWS * 4);
    float* scaleX = (float*)alloc((size_t)ROWS * 4);
    float* wvbar = (float*)alloc(EMBED * 4);
    float* vmean = (float*)alloc((size_t)ROWS * 4);
    int*   cnt   = (int*)alloc((size_t)ROWS * 4);
    int2*  cand  = (int2*)alloc((size_t)ROWS * CAP * 8);

    k_wvbar<<<EMBED, 256, 0, stream>>>(Wv, wvbar);
    // Row splits of the ORIGINAL Wq/Wk (no i8 quant for weights: X8=nullptr).
    k_xsplit_vmean<<<EMBED, 256, 0, stream>>>(Wq, wvbar, Wqhi, Wqlo, vmean, cnt, nullptr, nullptr);
    k_xsplit_vmean<<<EMBED, 256, 0, stream>>>(Wk, wvbar, Wkhi, Wklo, vmean, cnt, nullptr, nullptr);
    // M^T[b][a] = sum_n Wk[b][n]*Wq[a][n]
    k_gemm3<<<64, 256, 0, stream>>>(Wkhi, Wklo, Wqhi, Wqlo, MThi, MTlo);
    k_xsplit_vmean<<<ROWS, 256, 0, stream>>>(X, wvbar, Xhi, Xlo, vmean, cnt, X8, scaleX);  // real vmean+cnt=0+X8
    k_gemm3<<<1024, 256, 0, stream>>>(Xhi, Xlo, MThi, MTlo, Thi, Tlo);                     // T = X.M
    k_tquant<<<ROWS, 256, 0, stream>>>(Thi, T8, scaleT);                                   // T8 + scaleT
    k_scan<<<4096, 256, 0, stream>>>(T8, X8, scaleT, scaleX, cnt, cand);
    k_rescore<<<ROWS / 4, 256, 0, stream>>>(Thi, Tlo, X, vmean, cnt, cand, out);
}

// Round 11
// 450.284 us; speedup vs baseline: 1.1744x; 1.0304x over previous
//
#include <hip/hip_runtime.h>

#define EMBED 1024
#define BATCH 4
#define SEQ   4096
#define ROWS  (BATCH*SEQ)   // 16384
#define TSCAN_SC 140.0f     // scan margin, SCALED: 50 (proven) + i8 noise (r8/r10-proven)
#define TRES  160.0f        // rescore margin, scaled (r8/r10-proven)
#define KB2   64            // candidate regions per row: 32 kb-blocks x 2 k-half-waves
#define SLOT  8             // slots per region (Poisson lam~0.7 -> P(>8) ~ 1e-7)
#define RESCAP 192          // rescore survivor cap

typedef __attribute__((ext_vector_type(8))) short bf16x8;
typedef __attribute__((ext_vector_type(4))) float f32x4;
typedef __attribute__((ext_vector_type(4))) int   i32x4;

static __device__ __forceinline__ unsigned short f2bf(float x) {
    unsigned u = __float_as_uint(x);
    u = (u + 0x7fffu + ((u >> 16) & 1u)) >> 16;
    return (unsigned short)u;
}
static __device__ __forceinline__ float bf2f(unsigned short h) {
    return __uint_as_float(((unsigned)h) << 16);
}
static __device__ __forceinline__ void split2(float x, unsigned short& hi, unsigned short& lo) {
    hi = f2bf(x);
    lo = f2bf(x - bf2f(hi));
}

// ---- async global->LDS, one 16B segment ----
static __device__ __forceinline__ void gll(const unsigned short* g, unsigned short* l) {
    __builtin_amdgcn_global_load_lds(
        (const __attribute__((address_space(1))) unsigned int*)g,
        (__attribute__((address_space(3))) unsigned int*)l, 16, 0, 0);
}
static __device__ __forceinline__ void gllb(const unsigned char* g, unsigned char* l) {
    __builtin_amdgcn_global_load_lds(
        (const __attribute__((address_space(1))) unsigned int*)g,
        (__attribute__((address_space(3))) unsigned int*)l, 16, 0, 0);
}
// ---- 128x32-short tile stager, 4-segment swizzle (r3-proven, 0 conflicts) ----
static __device__ __forceinline__ void stage_tile(unsigned short (*lds)[32],
                                                  const unsigned short* gbase,
                                                  int wave, int lane) {
#pragma unroll
    for (int c = 0; c < 2; c++) {
        int L = wave * 128 + c * 64 + lane;
        int r = L >> 2, s = L & 3;
        int g = (s - (r >> 1)) & 3;
        gll(gbase + (size_t)r * EMBED + g * 8, &lds[r][s * 8]);
    }
}
static __device__ __forceinline__ bf16x8 read_frag(const unsigned short (*lds)[32], int r, int kq) {
    int s = ((kq >> 3) + (r >> 1)) & 3;
    return *(const bf16x8*)&lds[r][s * 8];
}
// ---- byte-identical i8 variants: 128 rows x 64 i8 = 4 x 16B segs/row, same swizzle (r8/r10-proven) ----
static __device__ __forceinline__ void stage_tile8(unsigned char (*lds)[64],
                                                   const unsigned char* gbase,
                                                   int wave, int lane) {
#pragma unroll
    for (int c = 0; c < 2; c++) {
        int L = wave * 128 + c * 64 + lane;
        int r = L >> 2, s = L & 3;
        int g = (s - (r >> 1)) & 3;
        gllb(gbase + (size_t)r * EMBED + g * 16, &lds[r][s * 16]);
    }
}
static __device__ __forceinline__ i32x4 read_frag8(const unsigned char (*lds)[64], int r, int kseg) {
    int s = (kseg + (r >> 1)) & 3;
    return *(const i32x4*)&lds[r][s * 16];
}

// ---------------- prep: wv_bar[i] = mean_d Wv[i][d] ----------------
__global__ void k_wvbar(const float* __restrict__ Wv, float* __restrict__ wvbar) {
    int r = blockIdx.x, t = threadIdx.x;
    float s = 0.f;
    for (int c = t; c < EMBED; c += 256) s += Wv[(size_t)r * EMBED + c];
    for (int d = 1; d < 64; d <<= 1) s += __shfl_xor(s, d);
    __shared__ float ws_[4];
    if ((t & 63) == 0) ws_[t >> 6] = s;
    __syncthreads();
    if (t == 0) wvbar[r] = (ws_[0] + ws_[1] + ws_[2] + ws_[3]) * (1.0f / EMBED);
}

// ---------------- prep: row split + vmean + cnt2 zero + (optional) i8 row-quant of X ----------------
__global__ __launch_bounds__(256) void k_xsplit_vmean(
    const float* __restrict__ X, const float* __restrict__ wvbar,
    unsigned short* __restrict__ Xhi, unsigned short* __restrict__ Xlo,
    float* __restrict__ vmean, int* __restrict__ cnt2,
    signed char* __restrict__ X8, float* __restrict__ scaleX) {
    int row = blockIdx.x, t = threadIdx.x;
    float4 x4 = *(const float4*)(X + (size_t)row * EMBED + t * 4);
    float4 w4 = *(const float4*)(wvbar + t * 4);
    ushort4 h, l;
    split2(x4.x, h.x, l.x); split2(x4.y, h.y, l.y);
    split2(x4.z, h.z, l.z); split2(x4.w, h.w, l.w);
    *(ushort4*)(Xhi + (size_t)row * EMBED + t * 4) = h;
    *(ushort4*)(Xlo + (size_t)row * EMBED + t * 4) = l;
    float s = x4.x * w4.x + x4.y * w4.y + x4.z * w4.z + x4.w * w4.w;
    float am = fmaxf(fmaxf(fabsf(x4.x), fabsf(x4.y)), fmaxf(fabsf(x4.z), fabsf(x4.w)));
    for (int d = 1; d < 64; d <<= 1) {
        s += __shfl_xor(s, d);
        am = fmaxf(am, __shfl_xor(am, d));
    }
    __shared__ float ws_[4], wa_[4];
    if ((t & 63) == 0) { ws_[t >> 6] = s; wa_[t >> 6] = am; }
    __syncthreads();
    if (t == 0) vmean[row] = ws_[0] + ws_[1] + ws_[2] + ws_[3];
    if (t < KB2) cnt2[(size_t)row * KB2 + t] = 0;
    if (X8) {
        float bm = fmaxf(fmaxf(wa_[0], wa_[1]), fmaxf(wa_[2], wa_[3]));
        bm = fmaxf(bm, 1e-20f);
        float inv = 127.0f / bm;
        char4 q;
        q.x = (signed char)(int)rintf(x4.x * inv);
        q.y = (signed char)(int)rintf(x4.y * inv);
        q.z = (signed char)(int)rintf(x4.z * inv);
        q.w = (signed char)(int)rintf(x4.w * inv);
        *(char4*)(X8 + (size_t)row * EMBED + t * 4) = q;
        if (t == 0) scaleX[row] = bm * (1.0f / 127.0f);
    }
}

// ---------------- prep: i8 row-quant of T (from Thi; scan only needs hi fidelity) ----------------
__global__ __launch_bounds__(256) void k_tquant(
    const unsigned short* __restrict__ Thi,
    signed char* __restrict__ T8, float* __restrict__ scaleT) {
    int row = blockIdx.x, t = threadIdx.x;
    ushort4 h = *(const ushort4*)(Thi + (size_t)row * EMBED + t * 4);
    float f0 = bf2f(h.x), f1 = bf2f(h.y), f2 = bf2f(h.z), f3 = bf2f(h.w);
    float am = fmaxf(fmaxf(fabsf(f0), fabsf(f1)), fmaxf(fabsf(f2), fabsf(f3)));
    for (int d = 1; d < 64; d <<= 1) am = fmaxf(am, __shfl_xor(am, d));
    __shared__ float wa_[4];
    if ((t & 63) == 0) wa_[t >> 6] = am;
    __syncthreads();
    float bm = fmaxf(fmaxf(fmaxf(wa_[0], wa_[1]), fmaxf(wa_[2], wa_[3])), 1e-20f);
    float inv = 127.0f / bm;
    char4 q;
    q.x = (signed char)(int)rintf(f0 * inv);
    q.y = (signed char)(int)rintf(f1 * inv);
    q.z = (signed char)(int)rintf(f2 * inv);
    q.w = (signed char)(int)rintf(f3 * inv);
    *(char4*)(T8 + (size_t)row * EMBED + t * 4) = q;
    if (t == 0) scaleT[row] = bm * (1.0f / 127.0f);
}

// ---------------- split-bf16 GEMM: C[row][col] = sum_k A[row][k]*B[col][k] (r4-proven) ----------------
__global__ __launch_bounds__(256) void k_gemm3(
    const unsigned short* __restrict__ Ahi, const unsigned short* __restrict__ Alo,
    const unsigned short* __restrict__ BThi, const unsigned short* __restrict__ BTlo,
    unsigned short* __restrict__ Chi, unsigned short* __restrict__ Clo) {
    __shared__ unsigned short Ah[128][32], Al[128][32], Bh[128][32], Bl[128][32];
    int bx = blockIdx.x;
    int bm = bx >> 3, bn = bx & 7;   // bn == XCD id under round-robin: B-tiles L2-local
    int tid = threadIdx.x, wave = tid >> 6, lane = tid & 63;
    int wm = (wave >> 1) * 64, wn = (wave & 1) * 64;
    int mrow = lane & 15, kq = (lane >> 4) * 8;

    f32x4 zero = {0.f, 0.f, 0.f, 0.f};
    f32x4 acc[4][4];
    for (int a = 0; a < 4; a++) for (int b = 0; b < 4; b++) acc[a][b] = zero;

    const unsigned short* Abase_h = Ahi + (size_t)(bm * 128) * EMBED;
    const unsigned short* Abase_l = Alo + (size_t)(bm * 128) * EMBED;
    const unsigned short* Bbase_h = BThi + (size_t)(bn * 128) * EMBED;
    const unsigned short* Bbase_l = BTlo + (size_t)(bn * 128) * EMBED;

    for (int k0 = 0; k0 < EMBED; k0 += 32) {
        __syncthreads();
        stage_tile(Ah, Abase_h + k0, wave, lane);
        stage_tile(Al, Abase_l + k0, wave, lane);
        stage_tile(Bh, Bbase_h + k0, wave, lane);
        stage_tile(Bl, Bbase_l + k0, wave, lane);
        __syncthreads();
        bf16x8 ah[4], al[4], bh[4], bl[4];
#pragma unroll
        for (int t = 0; t < 4; t++) {
            ah[t] = read_frag(Ah, wm + t * 16 + mrow, kq);
            al[t] = read_frag(Al, wm + t * 16 + mrow, kq);
            bh[t] = read_frag(Bh, wn + t * 16 + mrow, kq);
            bl[t] = read_frag(Bl, wn + t * 16 + mrow, kq);
        }
#pragma unroll
        for (int mt = 0; mt < 4; mt++)
#pragma unroll
            for (int nt = 0; nt < 4; nt++) {
                acc[mt][nt] = __builtin_amdgcn_mfma_f32_16x16x32_bf16(ah[mt], bh[nt], acc[mt][nt], 0, 0, 0);
                acc[mt][nt] = __builtin_amdgcn_mfma_f32_16x16x32_bf16(ah[mt], bl[nt], acc[mt][nt], 0, 0, 0);
                acc[mt][nt] = __builtin_amdgcn_mfma_f32_16x16x32_bf16(al[mt], bh[nt], acc[mt][nt], 0, 0, 0);
            }
    }
#pragma unroll
    for (int mt = 0; mt < 4; mt++)
#pragma unroll
        for (int nt = 0; nt < 4; nt++)
#pragma unroll
            for (int i = 0; i < 4; i++) {
                int row = bm * 128 + wm + mt * 16 + (lane >> 4) * 4 + i;
                int col = bn * 128 + wn + nt * 16 + (lane & 15);
                unsigned short h, l; split2(acc[mt][nt][i], h, l);
                Chi[(size_t)row * EMBED + col] = h;
                Clo[(size_t)row * EMBED + col] = l;
            }
}

// ---------------- scan: i8 loop (r10-proven, untouched) + atomic-free lean epilogue ----------------
// r21/r22 established: only epilogue cost and loop work move this kernel. r22 residual:
// VALUBusy 31.7% (scores computed twice; divergent leader-broadcast emit) + ~130 same-line
// global atomics/block (cnt lines shared by 32 blocks across XCDs). This round: (1) fold
// sX into scores ONCE in place (acc registers reused as float bits); threshold compare in
// RAW units (thr = rowmax_raw - TSCAN/st, one divide/row) so the *st multiply runs only for
// emitted candidates; (2) ZERO global atomics: each (row, 64-key half-window) owns a
// private 8-slot region cand2[row][kb*2+wc][8] + plain cnt2 store — no contention possible.
// Capacity 512 slots/row > proven CAP=128; per-window overflow P ~ 1e-7 (iid keys, lam~0.7).
__global__ __launch_bounds__(256, 3) void k_scan(
    const signed char* __restrict__ T8, const signed char* __restrict__ X8,
    const float* __restrict__ scaleT, const float* __restrict__ scaleX,
    int* __restrict__ cnt2, int2* __restrict__ cand2) {
    __shared__ unsigned char ThA[128][64], KhA[128][64];
    __shared__ unsigned char ThB[128][64], KhB[128][64];   // BK=128 as two K=64 units (32 KB)
    __shared__ float rowmax_[2][2][64];                    // RAW units (scaled/st)
    __shared__ float sT_[128], sX_[128];
    int bid = blockIdx.x;            // 0..4095
    int x   = bid & 7;               // XCD id; each XCD owns 4 fixed 128-key tiles per batch
    int i   = bid >> 3;
    int kbi = i & 3;
    int qb  = (i >> 2) & 31;
    int b   = i >> 7;
    int kb  = x * 4 + kbi;
    int tid = threadIdx.x, wave = tid >> 6, lane = tid & 63;
    int wr = wave >> 1, wc = wave & 1;
    int wq = wr * 64, wk = wc * 64;
    int mrow = lane & 15, kseg = lane >> 4;
    size_t qrow0 = (size_t)b * SEQ + (size_t)qb * 128;
    size_t krow0 = (size_t)b * SEQ + (size_t)kb * 128;
    const unsigned char* Tk = (const unsigned char*)T8 + qrow0 * EMBED;
    const unsigned char* Xk = (const unsigned char*)X8 + krow0 * EMBED;

    if (tid < 128) sT_[tid] = scaleT[qrow0 + tid];
    else           sX_[tid - 128] = scaleX[krow0 + tid - 128];

    i32x4 zero = {0, 0, 0, 0};
    i32x4 acc[4][4];
    for (int a = 0; a < 4; a++) for (int c = 0; c < 4; c++) acc[a][c] = zero;

    for (int k0 = 0; k0 < EMBED; k0 += 128) {
        __syncthreads();
        stage_tile8(ThA, Tk + k0,      wave, lane);
        stage_tile8(KhA, Xk + k0,      wave, lane);
        stage_tile8(ThB, Tk + k0 + 64, wave, lane);
        stage_tile8(KhB, Xk + k0 + 64, wave, lane);
        __syncthreads();
        {   // unit A (k0 .. k0+63)
            i32x4 ah[4], bh[4];
#pragma unroll
            for (int t = 0; t < 4; t++) {
                ah[t] = read_frag8(ThA, wq + t * 16 + mrow, kseg);
                bh[t] = read_frag8(KhA, wk + t * 16 + mrow, kseg);
            }
#pragma unroll
            for (int mt = 0; mt < 4; mt++)
#pragma unroll
                for (int nt = 0; nt < 4; nt++)
                    acc[mt][nt] = __builtin_amdgcn_mfma_i32_16x16x64_i8(ah[mt], bh[nt], acc[mt][nt], 0, 0, 0);
        }
        {   // unit B (k0+64 .. k0+127)
            i32x4 ah[4], bh[4];
#pragma unroll
            for (int t = 0; t < 4; t++) {
                ah[t] = read_frag8(ThB, wq + t * 16 + mrow, kseg);
                bh[t] = read_frag8(KhB, wk + t * 16 + mrow, kseg);
            }
#pragma unroll
            for (int mt = 0; mt < 4; mt++)
#pragma unroll
                for (int nt = 0; nt < 4; nt++)
                    acc[mt][nt] = __builtin_amdgcn_mfma_i32_16x16x64_i8(ah[mt], bh[nt], acc[mt][nt], 0, 0, 0);
        }
    }

    // ---- fold sX into scores ONCE, in place (raw units = scaled_score / st) ----
#pragma unroll
    for (int mt = 0; mt < 4; mt++)
#pragma unroll
        for (int nt = 0; nt < 4; nt++) {
            float sx = sX_[wk + nt * 16 + (lane & 15)];
#pragma unroll
            for (int i2 = 0; i2 < 4; i2++)
                acc[mt][nt][i2] = __float_as_int((float)acc[mt][nt][i2] * sx);
        }
    // ---- pass 1: per-row RAW max over this wave's 64 keys -> LDS exchange ----
#pragma unroll
    for (int mt = 0; mt < 4; mt++)
#pragma unroll
        for (int i2 = 0; i2 < 4; i2++) {
            float v = -INFINITY;
#pragma unroll
            for (int nt = 0; nt < 4; nt++) v = fmaxf(v, __int_as_float(acc[mt][nt][i2]));
#pragma unroll
            for (int d = 1; d < 16; d <<= 1) v = fmaxf(v, __shfl_xor(v, d));
            if ((lane & 15) == 0) rowmax_[wc][wr][mt * 16 + (lane >> 4) * 4 + i2] = v;
        }
    __syncthreads();
    // ---- pass 2: RAW-unit threshold over the full 128 keys; atomic-free region emit ----
#pragma unroll
    for (int mt = 0; mt < 4; mt++)
#pragma unroll
        for (int i2 = 0; i2 < 4; i2++) {
            int lr = mt * 16 + (lane >> 4) * 4 + i2;
            float st = sT_[wq + lr] * 0.03125f;
            float thr = fmaxf(rowmax_[0][wr][lr], rowmax_[1][wr][lr]) - TSCAN_SC / st;
            int grow = (int)qrow0 + wq + lr;
            int lpos = lane & 15;
            unsigned mm[4];
#pragma unroll
            for (int nt = 0; nt < 4; nt++) {
                unsigned long long bal = __ballot(__int_as_float(acc[mt][nt][i2]) >= thr);
                mm[nt] = (unsigned)((bal >> (lane & 48)) & 0xFFFFull);
            }
            int reg = (int)((size_t)grow * KB2) + kb * 2 + wc;
            int run = 0;
            unsigned below = (1u << lpos) - 1u;
#pragma unroll
            for (int nt = 0; nt < 4; nt++) {
                if (mm[nt] & (1u << lpos)) {
                    int slot = run + __popc(mm[nt] & below);
                    if (slot < SLOT) {
                        int gcol = (int)krow0 + wk + nt * 16 + lpos;
                        cand2[(size_t)reg * SLOT + slot] =
                            make_int2(gcol, __float_as_int(__int_as_float(acc[mt][nt][i2]) * st));
                    }
                }
                run += __popc(mm[nt]);
            }
            if (lpos == 0) cnt2[reg] = run < SLOT ? run : SLOT;   // run == tot here
        }
}

// ---------------- rescore: 4 rows per block, one wave per row, barrier-free ----------------
__global__ __launch_bounds__(256) void k_rescore(
    const unsigned short* __restrict__ Thi, const unsigned short* __restrict__ Tlo,
    const float* __restrict__ X, const float* __restrict__ vmean,
    const int* __restrict__ cnt2, const int2* __restrict__ cand2,
    float* __restrict__ out) {
    int wave = threadIdx.x >> 6, lane = threadIdx.x & 63;
    int row = blockIdx.x * 4 + wave;
    const int*  c2 = cnt2  + (size_t)row * KB2;
    const int2* cl = cand2 + (size_t)row * KB2 * SLOT;

    float smax = -INFINITY;
    for (int j = lane; j < KB2 * SLOT; j += 64) {
        int kb2 = j >> 3, s = j & (SLOT - 1);
        if (s < c2[kb2]) smax = fmaxf(smax, __int_as_float(cl[j].y));
    }
    for (int d = 1; d < 64; d <<= 1) smax = fmaxf(smax, __shfl_xor(smax, d));
    float th = smax - TRES;

    float q[16];
    {
        const unsigned short* qh = Thi + (size_t)row * EMBED + lane * 16;
        const unsigned short* ql = Tlo + (size_t)row * EMBED + lane * 16;
        bf16x8 h0 = *(const bf16x8*)qh, h1 = *(const bf16x8*)(qh + 8);
        bf16x8 l0 = *(const bf16x8*)ql, l1 = *(const bf16x8*)(ql + 8);
#pragma unroll
        for (int i = 0; i < 8; i++) {
            q[i]     = bf2f((unsigned short)h0[i]) + bf2f((unsigned short)l0[i]);
            q[i + 8] = bf2f((unsigned short)h1[i]) + bf2f((unsigned short)l1[i]);
        }
    }

    __shared__ int   sm_[4][RESCAP];
    __shared__ float sl_[4][RESCAP];
    __shared__ int   ns_[4];
    if (lane == 0) ns_[wave] = 0;
    for (int j = lane; j < KB2 * SLOT; j += 64) {
        int kb2 = j >> 3, s = j & (SLOT - 1);
        if (s < c2[kb2]) {
            int2 p = cl[j];
            if (__int_as_float(p.y) >= th) {
                int idx = atomicAdd(&ns_[wave], 1);
                if (idx < RESCAP) sm_[wave][idx] = p.x;
            }
        }
    }
    int ns = ns_[wave]; if (ns > RESCAP) ns = RESCAP;
    for (int t = 0; t < ns; t++) {
        int m = sm_[wave][t];
        const float* xr = X + (size_t)m * EMBED + lane * 16;
        float4 a0 = *(const float4*)(xr);
        float4 a1 = *(const float4*)(xr + 4);
        float4 a2 = *(const float4*)(xr + 8);
        float4 a3 = *(const float4*)(xr + 12);
        float dp = q[0]*a0.x + q[1]*a0.y + q[2]*a0.z + q[3]*a0.w
                 + q[4]*a1.x + q[5]*a1.y + q[6]*a1.z + q[7]*a1.w
                 + q[8]*a2.x + q[9]*a2.y + q[10]*a2.z + q[11]*a2.w
                 + q[12]*a3.x + q[13]*a3.y + q[14]*a3.z + q[15]*a3.w;
        for (int d = 1; d < 64; d <<= 1) dp += __shfl_xor(dp, d);
        if (lane == 0) sl_[wave][t] = dp * 0.03125f;
    }
    if (lane == 0) {
        float lm = -INFINITY;
        for (int t = 0; t < ns; t++) lm = fmaxf(lm, sl_[wave][t]);
        float den = 0.f, num = 0.f;
        for (int t = 0; t < ns; t++) {
            float e = __expf(sl_[wave][t] - lm);
            den += e;
            num += e * vmean[sm_[wave][t]];
        }
        out[row] = num / den;
    }
}

extern "C" void kernel_launch(void* const* d_in, const int* in_sizes, int n_in,
                              void* d_out, int out_size, void* d_ws, size_t ws_size,
                              hipStream_t stream) {
    const float* X  = (const float*)d_in[0];
    const float* Wq = (const float*)d_in[1];
    const float* Wk = (const float*)d_in[2];
    const float* Wv = (const float*)d_in[3];
    float* out = (float*)d_out;

    char* p = (char*)d_ws;
    auto alloc = [&](size_t bytes) -> void* {
        void* q = (void*)p;
        p += (bytes + 255) & ~(size_t)255;
        return q;
    };
    unsigned short* Wqhi = (unsigned short*)alloc((size_t)EMBED * EMBED * 2);
    unsigned short* Wqlo = (unsigned short*)alloc((size_t)EMBED * EMBED * 2);
    unsigned short* Wkhi = (unsigned short*)alloc((size_t)EMBED * EMBED * 2);
    unsigned short* Wklo = (unsigned short*)alloc((size_t)EMBED * EMBED * 2);
    unsigned short* MThi = (unsigned short*)alloc((size_t)EMBED * EMBED * 2);
    unsigned short* MTlo = (unsigned short*)alloc((size_t)EMBED * EMBED * 2);
    unsigned short* Xhi  = (unsigned short*)alloc((size_t)ROWS * EMBED * 2);
    unsigned short* Xlo  = (unsigned short*)alloc((size_t)ROWS * EMBED * 2);
    unsigned short* Thi  = (unsigned short*)alloc((size_t)ROWS * EMBED * 2);
    unsigned short* Tlo  = (unsigned short*)alloc((size_t)ROWS * EMBED * 2);
    signed char*    T8   = (signed char*)alloc((size_t)ROWS * EMBED);
    signed char*    X8   = (signed char*)alloc((size_t)ROWS * EMBED);
    float* scaleT = (float*)alloc((size_t)ROWS * 4);
    float* scaleX = (float*)alloc((size_t)ROWS * 4);
    float* wvbar = (float*)alloc(EMBED * 4);
    float* vmean = (float*)alloc((size_t)ROWS * 4);
    int*   cnt2  = (int*)alloc((size_t)ROWS * KB2 * 4);
    int2*  cand2 = (int2*)alloc((size_t)ROWS * KB2 * SLOT * 8);

    k_wvbar<<<EMBED, 256, 0, stream>>>(Wv, wvbar);
    // Row splits of the ORIGINAL Wq/Wk (no i8 quant for weights: X8=nullptr).
    k_xsplit_vmean<<<EMBED, 256, 0, stream>>>(Wq, wvbar, Wqhi, Wqlo, vmean, cnt2, nullptr, nullptr);
    k_xsplit_vmean<<<EMBED, 256, 0, stream>>>(Wk, wvbar, Wkhi, Wklo, vmean, cnt2, nullptr, nullptr);
    // M^T[b][a] = sum_n Wk[b][n]*Wq[a][n]
    k_gemm3<<<64, 256, 0, stream>>>(Wkhi, Wklo, Wqhi, Wqlo, MThi, MTlo);
    k_xsplit_vmean<<<ROWS, 256, 0, stream>>>(X, wvbar, Xhi, Xlo, vmean, cnt2, X8, scaleX);  // real vmean+cnt2=0+X8
    k_gemm3<<<1024, 256, 0, stream>>>(Xhi, Xlo, MThi, MTlo, Thi, Tlo);                      // T = X.M
    k_tquant<<<ROWS, 256, 0, stream>>>(Thi, T8, scaleT);                                    // T8 + scaleT
    k_scan<<<4096, 256, 0, stream>>>(T8, X8, scaleT, scaleX, cnt2, cand2);
    k_rescore<<<ROWS / 4, 256, 0, stream>>>(Thi, Tlo, X, vmean, cnt2, cand2, out);
}